// Round 3
// baseline (286.635 us; speedup 1.0000x reference)
//
#include <hip/hip_runtime.h>
#include <stdint.h>

typedef __bf16 bf16;
typedef bf16 bf16x2 __attribute__((ext_vector_type(2)));
typedef bf16 bf16x4 __attribute__((ext_vector_type(4)));
typedef bf16 bf16x8 __attribute__((ext_vector_type(8)));
typedef float f32x4 __attribute__((ext_vector_type(4)));
typedef float f32x16 __attribute__((ext_vector_type(16)));

static constexpr int Bc = 4, Sc = 1024, Ec = 1024, Hc = 16, Dc = 64, BSc = 4096;

__device__ __forceinline__ void gld_lds16(const void* g, void* s) {
  __builtin_amdgcn_global_load_lds((const __attribute__((address_space(1))) void*)g,
                                   (__attribute__((address_space(3))) void*)s, 16, 0, 0);
}

// ---------------------------------------------------------------------------
// Mask element-stride detection: u8 bool (stride 1) vs int32/float32 (stride 4).
// For 4-byte encodings of "true" (0x00000001 or 0x3F800000) every aligned
// 4-byte group contains a zero byte; u8 all-true gives groups with no zero.
__global__ void detect_mask_kernel(const uint8_t* __restrict__ mask, int* flag) {
  if (threadIdx.x == 0 && blockIdx.x == 0) {
    bool everyGroupHasZero = true;
    bool anyNonzero = false;
    for (int j = 0; j < 16; ++j) {
      bool z = false;
      for (int bjj = 0; bjj < 4; ++bjj) {
        uint8_t byte = mask[4 * j + bjj];
        if (byte == 0) z = true;
        if (byte != 0) anyNonzero = true;
      }
      if (!z) everyGroupHasZero = false;
    }
    *flag = (everyGroupHasZero && anyNonzero) ? 4 : 1;
  }
}

// ---------------------------------------------------------------------------
// fp32 -> bf16 for query/key_/value (3 x 4M elements)
__global__ __launch_bounds__(256) void convert_x_kernel(
    const float* __restrict__ q, const float* __restrict__ k, const float* __restrict__ v,
    bf16* __restrict__ xb) {
  const int n4 = (BSc * Ec) / 4;  // 1M float4 per tensor
  for (int i = blockIdx.x * blockDim.x + threadIdx.x; i < 3 * n4; i += gridDim.x * blockDim.x) {
    int which = i / n4;
    int off = i - which * n4;
    const float4* src = (which == 0) ? (const float4*)q : (which == 1) ? (const float4*)k : (const float4*)v;
    float4 f = src[off];
    bf16x4 o;
    o[0] = (bf16)f.x; o[1] = (bf16)f.y; o[2] = (bf16)f.z; o[3] = (bf16)f.w;
    *(bf16x4*)(xb + (size_t)which * BSc * Ec + (size_t)off * 4) = o;
  }
}

// ---------------------------------------------------------------------------
// W [K][N] fp32 -> WT [N][K] bf16 (so GEMM B-fragments read contiguous K)
__global__ __launch_bounds__(256) void convtrans_w_kernel(
    const float* __restrict__ Wq, const float* __restrict__ Wk,
    const float* __restrict__ Wv, const float* __restrict__ Wo,
    bf16* __restrict__ wT) {
  __shared__ float tile[64][65];
  const int k0 = blockIdx.x * 64, n0 = blockIdx.y * 64, z = blockIdx.z;
  const float* W = (z == 0) ? Wq : (z == 1) ? Wk : (z == 2) ? Wv : Wo;
  bf16* out = wT + (size_t)z * Ec * Ec;
  const int t = threadIdx.x;
#pragma unroll
  for (int p = 0; p < 16; p++) {
    int r = p * 4 + (t >> 6), c = t & 63;
    tile[r][c] = W[(size_t)(k0 + r) * Ec + n0 + c];
  }
  __syncthreads();
#pragma unroll
  for (int p = 0; p < 8; p++) {
    int n = p * 8 + (t >> 5), kk = (t & 31) * 2;
    bf16x2 v2;
    v2[0] = (bf16)tile[kk][n];
    v2[1] = (bf16)tile[kk + 1][n];
    *(bf16x2*)(out + (size_t)(n0 + n) * Ec + k0 + kk) = v2;
  }
}

// ---------------------------------------------------------------------------
// 128x128-tile bf16 GEMM (m97 structure): C = A @ WT^T + bias.
// A [4096][1024] bf16 row-major, WT [1024 n][1024 k] bf16 row-major.
// MODE 0: fp32 plain [M][N] output.  MODE 1: bf16 head-split [B,H,S,D] output,
//         one 4M-element tensor per blockIdx.z (Qb/Kb/Vb contiguous).
template <int MODE>
__global__ __launch_bounds__(256) void gemm128_kernel(
    const bf16* __restrict__ A_, const bf16* __restrict__ W_,
    const float* __restrict__ bias0, const float* __restrict__ bias1, const float* __restrict__ bias2,
    bf16* __restrict__ outb_, float* __restrict__ outf) {
  constexpr int K = 1024, N = 1024;
  const int z = blockIdx.z;
  const bf16* A = A_ + (size_t)z * BSc * K;
  const bf16* Wt = W_ + (size_t)z * N * K;
  const float* bias = (z == 0) ? bias0 : (z == 1) ? bias1 : bias2;
  bf16* outb = outb_ + (size_t)z * Bc * Hc * Sc * Dc;
  const int n0 = blockIdx.x * 128, m0 = blockIdx.y * 128;

  __shared__ bf16 As[128 * 64];
  __shared__ bf16 Bs[128 * 64];
  const int t = threadIdx.x, wave = t >> 6, lane = t & 63;
  const int wr = wave >> 1, wc = wave & 1;

  f32x4 acc[4][4];
#pragma unroll
  for (int i = 0; i < 4; i++)
#pragma unroll
    for (int j = 0; j < 4; j++)
#pragma unroll
      for (int r = 0; r < 4; r++) acc[i][j][r] = 0.f;

  const int srow = (lane >> 3);
  const int scol = (lane & 7) * 8;

  for (int kt = 0; kt < K; kt += 64) {
#pragma unroll
    for (int i = 0; i < 4; i++) {
      const int chunk = i * 4 + wave;  // 0..15, wave-uniform
      const int row = chunk * 8 + srow;
      gld_lds16(A + (size_t)(m0 + row) * K + kt + scol, &As[chunk * 512]);
      gld_lds16(Wt + (size_t)(n0 + row) * K + kt + scol, &Bs[chunk * 512]);
    }
    __syncthreads();
#pragma unroll
    for (int kk = 0; kk < 2; kk++) {
      bf16x8 af[4], bg[4];
#pragma unroll
      for (int i = 0; i < 4; i++) {
        af[i] = *(const bf16x8*)&As[(64 * wr + i * 16 + (lane & 15)) * 64 + kk * 32 + (lane >> 4) * 8];
        bg[i] = *(const bf16x8*)&Bs[(64 * wc + i * 16 + (lane & 15)) * 64 + kk * 32 + (lane >> 4) * 8];
      }
#pragma unroll
      for (int mi = 0; mi < 4; mi++)
#pragma unroll
        for (int ni = 0; ni < 4; ni++)
          acc[mi][ni] = __builtin_amdgcn_mfma_f32_16x16x32_bf16(af[mi], bg[ni], acc[mi][ni], 0, 0, 0);
    }
    __syncthreads();
  }

#pragma unroll
  for (int mi = 0; mi < 4; mi++) {
#pragma unroll
    for (int ni = 0; ni < 4; ni++) {
      const int col = n0 + 64 * wc + ni * 16 + (lane & 15);
      const float bvl = bias[col];
#pragma unroll
      for (int r = 0; r < 4; r++) {
        const int row = m0 + 64 * wr + mi * 16 + (lane >> 4) * 4 + r;
        const float v = acc[mi][ni][r] + bvl;
        if (MODE == 0) {
          outf[(size_t)row * N + col] = v;
        } else {
          const int bidx = row >> 10, s = row & 1023, hh = col >> 6, d = col & 63;
          outb[(((size_t)bidx * Hc + hh) * Sc + s) * Dc + d] = (bf16)v;
        }
      }
    }
  }
}

// ---------------------------------------------------------------------------
// V [bh][S][D] -> VT [bh][D][S] (bf16), 64x64 LDS tiles
__global__ __launch_bounds__(256) void transpose_v_kernel(const bf16* __restrict__ Vb,
                                                          bf16* __restrict__ VTb) {
  __shared__ bf16 tile[64][66];
  const int s0 = blockIdx.x * 64, bh = blockIdx.y;
  const bf16* src = Vb + (size_t)bh * Sc * Dc;
  bf16* dst = VTb + (size_t)bh * Dc * Sc;
  const int t = threadIdx.x;
#pragma unroll
  for (int p = 0; p < 8; p++) {
    int s = p * 8 + (t >> 5), d = (t & 31) * 2;
    *(bf16x2*)&tile[s][d] = *(const bf16x2*)(src + (size_t)(s0 + s) * Dc + d);
  }
  __syncthreads();
#pragma unroll
  for (int p = 0; p < 8; p++) {
    int d = p * 8 + (t >> 5), s = (t & 31) * 2;
    bf16x2 v2;
    v2[0] = tile[s][d];
    v2[1] = tile[s + 1][d];
    *(bf16x2*)(dst + (size_t)d * Sc + s0 + s) = v2;
  }
}

// ---------------------------------------------------------------------------
// Fused attention: per WG (b, h, 32 q-rows). 4 waves, wave w owns k in
// [w*256, w*256+256). Swapped QK^T (D[k][q]) -> lane-local softmax row,
// with CROSS-WAVE max/sum reduction through LDS (the round-2 bug fix).
__global__ __launch_bounds__(256) void attn_kernel(
    const bf16* __restrict__ Qb, const bf16* __restrict__ Kb, const bf16* __restrict__ VTb,
    const uint8_t* __restrict__ mask, const int* __restrict__ mflag,
    float* __restrict__ wout_, bf16* __restrict__ ctx) {
  const int q0 = blockIdx.x * 32, h = blockIdx.y, b = blockIdx.z;
  const int bh = b * Hc + h;
  const int t = threadIdx.x, wave = t >> 6, lane = t & 63;
  const int l31 = lane & 31, hi = lane >> 5;
  const int q = q0 + l31;
  const int mstride = *mflag;

  __shared__ float redmax[4][32];
  __shared__ float redsum[4][32];

  // Q B-fragments (col = q), kept in registers for the whole QK phase
  const bf16* Qp = Qb + ((size_t)bh * Sc + q) * Dc;
  bf16x8 qf[4];
#pragma unroll
  for (int ks = 0; ks < 4; ks++) qf[ks] = *(const bf16x8*)(Qp + ks * 16 + hi * 8);

  const int kbase = wave * 256;
  const bf16* Kbh = Kb + (size_t)bh * Sc * Dc;

  // ---- scores: 8 tiles of 32k x 32q, D[k][q]
  f32x16 sc[8];
#pragma unroll
  for (int tt = 0; tt < 8; tt++) {
    const bf16* Kp = Kbh + (size_t)(kbase + tt * 32 + l31) * Dc;
    f32x16 a;
#pragma unroll
    for (int r = 0; r < 16; r++) a[r] = 0.f;
#pragma unroll
    for (int ks = 0; ks < 4; ks++) {
      bf16x8 kf = *(const bf16x8*)(Kp + ks * 16 + hi * 8);
      a = __builtin_amdgcn_mfma_f32_32x32x16_bf16(kf, qf[ks], a, 0, 0, 0);
    }
    sc[tt] = a;
  }

  // ---- scale + mask (klocal for reg = (reg&3) + 8*(reg>>2) + 4*hi)
  if (mstride == 1) {
    const uint8_t* mrow = mask + (size_t)(b * Sc + q) * Sc;
#pragma unroll
    for (int tt = 0; tt < 8; tt++) {
#pragma unroll
      for (int g = 0; g < 4; g++) {
        const int kg = kbase + tt * 32 + g * 8 + hi * 4;
        const uint32_t mw = *(const uint32_t*)(mrow + kg);
#pragma unroll
        for (int r = 0; r < 4; r++) {
          float s = sc[tt][g * 4 + r] * 0.125f;
          if (((mw >> (8 * r)) & 0xffu) == 0u) s = -1e9f;  // byte==0 -> masked
          sc[tt][g * 4 + r] = s;
        }
      }
    }
  } else {
    const uint8_t* mrow = mask + (size_t)(b * Sc + q) * Sc * 4;
#pragma unroll
    for (int tt = 0; tt < 8; tt++) {
#pragma unroll
      for (int g = 0; g < 4; g++) {
        const int kg = kbase + tt * 32 + g * 8 + hi * 4;
        const uint4 m4 = *(const uint4*)(mrow + (size_t)4 * kg);
        // whole-word nonzero test: works for int32 (1) and float32 (1.0f) truths
        const uint32_t w[4] = {m4.x, m4.y, m4.z, m4.w};
#pragma unroll
        for (int r = 0; r < 4; r++) {
          float s = sc[tt][g * 4 + r] * 0.125f;
          if (w[r] == 0u) s = -1e9f;
          sc[tt][g * 4 + r] = s;
        }
      }
    }
  }

  // ---- softmax: lane-local -> xor-32 (pair covers this wave's 256 k)
  //              -> LDS cross-wave reduction (global max/denominator per q)
  float mx = -3.0e38f;
#pragma unroll
  for (int tt = 0; tt < 8; tt++)
#pragma unroll
    for (int r = 0; r < 16; r++) mx = fmaxf(mx, sc[tt][r]);
  mx = fmaxf(mx, __shfl_xor(mx, 32));
  if (hi == 0) redmax[wave][l31] = mx;
  __syncthreads();
  mx = fmaxf(fmaxf(redmax[0][l31], redmax[1][l31]),
             fmaxf(redmax[2][l31], redmax[3][l31]));

  float lsum = 0.f;
#pragma unroll
  for (int tt = 0; tt < 8; tt++)
#pragma unroll
    for (int r = 0; r < 16; r++) {
      float e = __expf(sc[tt][r] - mx);
      sc[tt][r] = e;
      lsum += e;
    }
  lsum += __shfl_xor(lsum, 32);
  if (hi == 0) redsum[wave][l31] = lsum;
  __syncthreads();
  const float tot = redsum[0][l31] + redsum[1][l31] + redsum[2][l31] + redsum[3][l31];
  const float inv = 1.f / tot;
#pragma unroll
  for (int tt = 0; tt < 8; tt++)
#pragma unroll
    for (int r = 0; r < 16; r++) sc[tt][r] *= inv;

  // ---- write attn_weights (row q, float4 per reg-group; halves disjoint in k)
  float* wrow = wout_ + ((size_t)bh * Sc + q) * Sc;
#pragma unroll
  for (int tt = 0; tt < 8; tt++) {
#pragma unroll
    for (int g = 0; g < 4; g++) {
      float4 w4;
      w4.x = sc[tt][g * 4 + 0];
      w4.y = sc[tt][g * 4 + 1];
      w4.z = sc[tt][g * 4 + 2];
      w4.w = sc[tt][g * 4 + 3];
      *(float4*)(wrow + kbase + tt * 32 + g * 8 + hi * 4) = w4;
    }
  }

  // ---- PV: O[q][d] partial over this wave's k-range.
  // A-fragment (P[q][k], 8 consecutive k) assembled in-register via shfl_xor(32).
  const bf16* VTbh = VTb + (size_t)bh * Dc * Sc;
  f32x16 oacc[2];
#pragma unroll
  for (int nj = 0; nj < 2; nj++)
#pragma unroll
    for (int r = 0; r < 16; r++) oacc[nj][r] = 0.f;

#pragma unroll
  for (int tt = 0; tt < 8; tt++) {
    const int k0 = kbase + tt * 32;
#pragma unroll
    for (int st = 0; st < 2; st++) {
      bf16x8 pa;
#pragma unroll
      for (int r = 0; r < 4; r++) {
        const float own = hi ? sc[tt][8 * st + 4 + r] : sc[tt][8 * st + r];
        const float oth = hi ? sc[tt][8 * st + r] : sc[tt][8 * st + 4 + r];
        const float rec = __shfl_xor(oth, 32);
        pa[r] = (bf16)(hi ? rec : own);
        pa[4 + r] = (bf16)(hi ? own : rec);
      }
#pragma unroll
      for (int nj = 0; nj < 2; nj++) {
        const bf16x8 bv = *(const bf16x8*)(VTbh + (size_t)(nj * 32 + l31) * Sc + k0 + st * 16 + hi * 8);
        oacc[nj] = __builtin_amdgcn_mfma_f32_32x32x16_bf16(pa, bv, oacc[nj], 0, 0, 0);
      }
    }
  }

  // ---- cross-wave O reduction + ctx write ([B*S][E] bf16)
  __shared__ float Os[4][32][64];
#pragma unroll
  for (int nj = 0; nj < 2; nj++)
#pragma unroll
    for (int rg = 0; rg < 16; rg++) {
      const int qq = (rg & 3) + 8 * (rg >> 2) + 4 * hi;
      Os[wave][qq][nj * 32 + l31] = oacc[nj][rg];
    }
  __syncthreads();
  {
    const int qq = t >> 3, dd = (t & 7) * 8;
    bf16x8 ov;
#pragma unroll
    for (int j = 0; j < 8; j++) {
      const float vs = Os[0][qq][dd + j] + Os[1][qq][dd + j] + Os[2][qq][dd + j] + Os[3][qq][dd + j];
      ov[j] = (bf16)vs;
    }
    *(bf16x8*)(ctx + ((size_t)(b * Sc + q0 + qq)) * Ec + h * Dc + dd) = ov;
  }
}

// ---------------------------------------------------------------------------
extern "C" void kernel_launch(void* const* d_in, const int* in_sizes, int n_in,
                              void* d_out, int out_size, void* d_ws, size_t ws_size,
                              hipStream_t stream) {
  const float* q = (const float*)d_in[0];
  const float* k = (const float*)d_in[1];
  const float* v = (const float*)d_in[2];
  const uint8_t* mask = (const uint8_t*)d_in[3];
  const float* Wq = (const float*)d_in[4];
  const float* bq = (const float*)d_in[5];
  const float* Wk = (const float*)d_in[6];
  const float* bk = (const float*)d_in[7];
  const float* Wv = (const float*)d_in[8];
  const float* bv = (const float*)d_in[9];
  const float* Wo = (const float*)d_in[10];
  const float* bo = (const float*)d_in[11];

  // Workspace map (bf16 elements unless noted), ~56MB + 4B:
  //   [0,12M): xb (query,key_,value bf16); [0,4M) reused as ctx after GEMMs,
  //   [4M,8M) reused as VT after projection GEMMs.
  //   [12M,16M): wT (Wq,Wk,Wv,Wo transposed bf16)
  //   [16M,28M): Qb, Kb, Vb head-split bf16 (contiguous -> z-offset in gemm)
  //   byte offset 56MB: mask-stride flag (int)
  bf16* wsb = (bf16*)d_ws;
  bf16* xb = wsb;
  bf16* ctx = wsb;                               // reuse (safe: xb consumed before attn)
  bf16* VTb = wsb + (size_t)4 * 1024 * 1024;     // reuse of xb key region (after gemm_proj)
  bf16* wT = wsb + (size_t)12 * 1024 * 1024;
  bf16* Qb = wsb + (size_t)16 * 1024 * 1024;
  bf16* Kb = wsb + (size_t)20 * 1024 * 1024;
  bf16* Vb = wsb + (size_t)24 * 1024 * 1024;
  int* mflag = (int*)((char*)d_ws + (size_t)56 * 1024 * 1024);

  float* outf = (float*)d_out;                   // attn_output [4,1024,1024]
  float* attnw = outf + (size_t)4 * 1024 * 1024; // attn_weights [4,16,1024,1024]

  detect_mask_kernel<<<1, 64, 0, stream>>>(mask, mflag);
  convert_x_kernel<<<2048, 256, 0, stream>>>(q, k, v, xb);
  convtrans_w_kernel<<<dim3(16, 16, 4), 256, 0, stream>>>(Wq, Wk, Wv, Wo, wT);
  gemm128_kernel<1><<<dim3(8, 32, 3), 256, 0, stream>>>(xb, wT, bq, bk, bv, Qb, nullptr);
  transpose_v_kernel<<<dim3(16, 64), 256, 0, stream>>>(Vb, VTb);
  attn_kernel<<<dim3(32, 16, 4), 256, 0, stream>>>(Qb, Kb, VTb, mask, mflag, attnw, ctx);
  gemm128_kernel<0><<<dim3(8, 32, 1), 256, 0, stream>>>(ctx, wT + (size_t)3 * 1024 * 1024,
                                                        bo, bo, bo, nullptr, outf);
}

// Round 4
// 281.136 us; speedup vs baseline: 1.0196x; 1.0196x over previous
//
#include <hip/hip_runtime.h>
#include <stdint.h>

typedef __bf16 bf16;
typedef bf16 bf16x2 __attribute__((ext_vector_type(2)));
typedef bf16 bf16x4 __attribute__((ext_vector_type(4)));
typedef bf16 bf16x8 __attribute__((ext_vector_type(8)));
typedef float f32x4 __attribute__((ext_vector_type(4)));
typedef float f32x16 __attribute__((ext_vector_type(16)));

static constexpr int Bc = 4, Sc = 1024, Ec = 1024, Hc = 16, Dc = 64, BSc = 4096;

__device__ __forceinline__ void gld_lds16(const void* g, void* s) {
  __builtin_amdgcn_global_load_lds((const __attribute__((address_space(1))) void*)g,
                                   (__attribute__((address_space(3))) void*)s, 16, 0, 0);
}

// ---------------------------------------------------------------------------
// Mask element-stride detection: u8 bool (stride 1) vs int32/float32 (stride 4).
// For 4-byte encodings of "true" (0x00000001 or 0x3F800000) every aligned
// 4-byte group contains a zero byte; u8 all-true gives groups with no zero.
__global__ void detect_mask_kernel(const uint8_t* __restrict__ mask, int* flag) {
  if (threadIdx.x == 0 && blockIdx.x == 0) {
    bool everyGroupHasZero = true;
    bool anyNonzero = false;
    for (int j = 0; j < 16; ++j) {
      bool z = false;
      for (int bjj = 0; bjj < 4; ++bjj) {
        uint8_t byte = mask[4 * j + bjj];
        if (byte == 0) z = true;
        if (byte != 0) anyNonzero = true;
      }
      if (!z) everyGroupHasZero = false;
    }
    *flag = (everyGroupHasZero && anyNonzero) ? 4 : 1;
  }
}

// ---------------------------------------------------------------------------
// fp32 -> bf16 for query/key_/value (3 x 4M elements)
__global__ __launch_bounds__(256) void convert_x_kernel(
    const float* __restrict__ q, const float* __restrict__ k, const float* __restrict__ v,
    bf16* __restrict__ xb) {
  const int n4 = (BSc * Ec) / 4;  // 1M float4 per tensor
  for (int i = blockIdx.x * blockDim.x + threadIdx.x; i < 3 * n4; i += gridDim.x * blockDim.x) {
    int which = i / n4;
    int off = i - which * n4;
    const float4* src = (which == 0) ? (const float4*)q : (which == 1) ? (const float4*)k : (const float4*)v;
    float4 f = src[off];
    bf16x4 o;
    o[0] = (bf16)f.x; o[1] = (bf16)f.y; o[2] = (bf16)f.z; o[3] = (bf16)f.w;
    *(bf16x4*)(xb + (size_t)which * BSc * Ec + (size_t)off * 4) = o;
  }
}

// ---------------------------------------------------------------------------
// W [K][N] fp32 -> WT [N][K] bf16 (so GEMM B-fragments read contiguous K)
__global__ __launch_bounds__(256) void convtrans_w_kernel(
    const float* __restrict__ Wq, const float* __restrict__ Wk,
    const float* __restrict__ Wv, const float* __restrict__ Wo,
    bf16* __restrict__ wT) {
  __shared__ float tile[64][65];
  const int k0 = blockIdx.x * 64, n0 = blockIdx.y * 64, z = blockIdx.z;
  const float* W = (z == 0) ? Wq : (z == 1) ? Wk : (z == 2) ? Wv : Wo;
  bf16* out = wT + (size_t)z * Ec * Ec;
  const int t = threadIdx.x;
#pragma unroll
  for (int p = 0; p < 16; p++) {
    int r = p * 4 + (t >> 6), c = t & 63;
    tile[r][c] = W[(size_t)(k0 + r) * Ec + n0 + c];
  }
  __syncthreads();
#pragma unroll
  for (int p = 0; p < 8; p++) {
    int n = p * 8 + (t >> 5), kk = (t & 31) * 2;
    bf16x2 v2;
    v2[0] = (bf16)tile[kk][n];
    v2[1] = (bf16)tile[kk + 1][n];
    *(bf16x2*)(out + (size_t)(n0 + n) * Ec + k0 + kk) = v2;
  }
}

// ---------------------------------------------------------------------------
// 128x128-tile bf16 GEMM (m97 structure): C = A @ WT^T + bias.
// MODE 0: fp32 plain [M][N] output.  MODE 1: bf16 head-split [B,H,S,D] output,
//         one 4M-element tensor per blockIdx.z (Qb/Kb/Vb contiguous).
template <int MODE>
__global__ __launch_bounds__(256) void gemm128_kernel(
    const bf16* __restrict__ A_, const bf16* __restrict__ W_,
    const float* __restrict__ bias0, const float* __restrict__ bias1, const float* __restrict__ bias2,
    bf16* __restrict__ outb_, float* __restrict__ outf) {
  constexpr int K = 1024, N = 1024;
  const int z = blockIdx.z;
  const bf16* A = A_ + (size_t)z * BSc * K;
  const bf16* Wt = W_ + (size_t)z * N * K;
  const float* bias = (z == 0) ? bias0 : (z == 1) ? bias1 : bias2;
  bf16* outb = outb_ + (size_t)z * Bc * Hc * Sc * Dc;
  const int n0 = blockIdx.x * 128, m0 = blockIdx.y * 128;

  __shared__ bf16 As[128 * 64];
  __shared__ bf16 Bs[128 * 64];
  const int t = threadIdx.x, wave = t >> 6, lane = t & 63;
  const int wr = wave >> 1, wc = wave & 1;

  f32x4 acc[4][4];
#pragma unroll
  for (int i = 0; i < 4; i++)
#pragma unroll
    for (int j = 0; j < 4; j++)
#pragma unroll
      for (int r = 0; r < 4; r++) acc[i][j][r] = 0.f;

  const int srow = (lane >> 3);
  const int scol = (lane & 7) * 8;

  for (int kt = 0; kt < K; kt += 64) {
#pragma unroll
    for (int i = 0; i < 4; i++) {
      const int chunk = i * 4 + wave;  // 0..15, wave-uniform
      const int row = chunk * 8 + srow;
      gld_lds16(A + (size_t)(m0 + row) * K + kt + scol, &As[chunk * 512]);
      gld_lds16(Wt + (size_t)(n0 + row) * K + kt + scol, &Bs[chunk * 512]);
    }
    __syncthreads();
#pragma unroll
    for (int kk = 0; kk < 2; kk++) {
      bf16x8 af[4], bg[4];
#pragma unroll
      for (int i = 0; i < 4; i++) {
        af[i] = *(const bf16x8*)&As[(64 * wr + i * 16 + (lane & 15)) * 64 + kk * 32 + (lane >> 4) * 8];
        bg[i] = *(const bf16x8*)&Bs[(64 * wc + i * 16 + (lane & 15)) * 64 + kk * 32 + (lane >> 4) * 8];
      }
#pragma unroll
      for (int mi = 0; mi < 4; mi++)
#pragma unroll
        for (int ni = 0; ni < 4; ni++)
          acc[mi][ni] = __builtin_amdgcn_mfma_f32_16x16x32_bf16(af[mi], bg[ni], acc[mi][ni], 0, 0, 0);
    }
    __syncthreads();
  }

#pragma unroll
  for (int mi = 0; mi < 4; mi++) {
#pragma unroll
    for (int ni = 0; ni < 4; ni++) {
      const int col = n0 + 64 * wc + ni * 16 + (lane & 15);
      const float bvl = bias[col];
#pragma unroll
      for (int r = 0; r < 4; r++) {
        const int row = m0 + 64 * wr + mi * 16 + (lane >> 4) * 4 + r;
        const float v = acc[mi][ni][r] + bvl;
        if (MODE == 0) {
          outf[(size_t)row * N + col] = v;
        } else {
          const int bidx = row >> 10, s = row & 1023, hh = col >> 6, d = col & 63;
          outb[(((size_t)bidx * Hc + hh) * Sc + s) * Dc + d] = (bf16)v;
        }
      }
    }
  }
}

// ---------------------------------------------------------------------------
// V [bh][S][D] -> VT [bh][D][S] (bf16), 64x64 LDS tiles
__global__ __launch_bounds__(256) void transpose_v_kernel(const bf16* __restrict__ Vb,
                                                          bf16* __restrict__ VTb) {
  __shared__ bf16 tile[64][66];
  const int s0 = blockIdx.x * 64, bh = blockIdx.y;
  const bf16* src = Vb + (size_t)bh * Sc * Dc;
  bf16* dst = VTb + (size_t)bh * Dc * Sc;
  const int t = threadIdx.x;
#pragma unroll
  for (int p = 0; p < 8; p++) {
    int s = p * 8 + (t >> 5), d = (t & 31) * 2;
    *(bf16x2*)&tile[s][d] = *(const bf16x2*)(src + (size_t)(s0 + s) * Dc + d);
  }
  __syncthreads();
#pragma unroll
  for (int p = 0; p < 8; p++) {
    int d = p * 8 + (t >> 5), s = (t & 31) * 2;
    bf16x2 v2;
    v2[0] = tile[s][d];
    v2[1] = tile[s + 1][d];
    *(bf16x2*)(dst + (size_t)d * Sc + s0 + s) = v2;
  }
}

// ---------------------------------------------------------------------------
// Fused attention, 8-wave version (round-4 restructure for occupancy):
// per WG (b, h, 32 q-rows), 512 threads. Wave w owns k in [w*128, w*128+128)
// -> sc[4] (64 VGPR) instead of sc[8] (128 VGPR). Swapped QK^T (D[k][q]),
// lane-local softmax + xor32 + 8-wave LDS reduction. Two-stage O reduction.
__global__ __launch_bounds__(512, 3) void attn_kernel(
    const bf16* __restrict__ Qb, const bf16* __restrict__ Kb, const bf16* __restrict__ VTb,
    const uint8_t* __restrict__ mask, const int* __restrict__ mflag,
    float* __restrict__ wout_, bf16* __restrict__ ctx) {
  const int q0 = blockIdx.x * 32, h = blockIdx.y, b = blockIdx.z;
  const int bh = b * Hc + h;
  const int t = threadIdx.x, wave = t >> 6, lane = t & 63;
  const int l31 = lane & 31, hi = lane >> 5;
  const int q = q0 + l31;
  const int mstride = *mflag;

  __shared__ float redmax[8][32];
  __shared__ float redsum[8][32];
  __shared__ float Os[4][32][65];  // +1 pad: final-reduce reads 2-way not 16-way

  // Q B-fragments (col = q); all waves load the same 4KB (L1-cached)
  const bf16* Qp = Qb + ((size_t)bh * Sc + q) * Dc;
  bf16x8 qf[4];
#pragma unroll
  for (int ks = 0; ks < 4; ks++) qf[ks] = *(const bf16x8*)(Qp + ks * 16 + hi * 8);

  const int kbase = wave * 128;
  const bf16* Kbh = Kb + (size_t)bh * Sc * Dc;

  // ---- scores: 4 tiles of 32k x 32q, D[k][q]
  f32x16 sc[4];
#pragma unroll
  for (int tt = 0; tt < 4; tt++) {
    const bf16* Kp = Kbh + (size_t)(kbase + tt * 32 + l31) * Dc;
    f32x16 a;
#pragma unroll
    for (int r = 0; r < 16; r++) a[r] = 0.f;
#pragma unroll
    for (int ks = 0; ks < 4; ks++) {
      bf16x8 kf = *(const bf16x8*)(Kp + ks * 16 + hi * 8);
      a = __builtin_amdgcn_mfma_f32_32x32x16_bf16(kf, qf[ks], a, 0, 0, 0);
    }
    sc[tt] = a;
  }

  // ---- scale + mask (klocal for reg = (reg&3) + 8*(reg>>2) + 4*hi)
  if (mstride == 1) {
    const uint8_t* mrow = mask + (size_t)(b * Sc + q) * Sc;
#pragma unroll
    for (int tt = 0; tt < 4; tt++) {
#pragma unroll
      for (int g = 0; g < 4; g++) {
        const int kg = kbase + tt * 32 + g * 8 + hi * 4;
        const uint32_t mw = *(const uint32_t*)(mrow + kg);
#pragma unroll
        for (int r = 0; r < 4; r++) {
          float s = sc[tt][g * 4 + r] * 0.125f;
          if (((mw >> (8 * r)) & 0xffu) == 0u) s = -1e9f;  // byte==0 -> masked
          sc[tt][g * 4 + r] = s;
        }
      }
    }
  } else {
    const uint8_t* mrow = mask + (size_t)(b * Sc + q) * Sc * 4;
#pragma unroll
    for (int tt = 0; tt < 4; tt++) {
#pragma unroll
      for (int g = 0; g < 4; g++) {
        const int kg = kbase + tt * 32 + g * 8 + hi * 4;
        const uint4 m4 = *(const uint4*)(mrow + (size_t)4 * kg);
        // whole-word nonzero test: works for int32 (1) and float32 (1.0f) truths
        const uint32_t w[4] = {m4.x, m4.y, m4.z, m4.w};
#pragma unroll
        for (int r = 0; r < 4; r++) {
          float s = sc[tt][g * 4 + r] * 0.125f;
          if (w[r] == 0u) s = -1e9f;
          sc[tt][g * 4 + r] = s;
        }
      }
    }
  }

  // ---- softmax: lane-local -> xor-32 (covers wave's 128 k)
  //              -> LDS cross-wave reduction over 8 waves
  float mx = -3.0e38f;
#pragma unroll
  for (int tt = 0; tt < 4; tt++)
#pragma unroll
    for (int r = 0; r < 16; r++) mx = fmaxf(mx, sc[tt][r]);
  mx = fmaxf(mx, __shfl_xor(mx, 32));
  if (hi == 0) redmax[wave][l31] = mx;
  __syncthreads();
#pragma unroll
  for (int w8 = 0; w8 < 8; w8++) mx = fmaxf(mx, redmax[w8][l31]);

  float lsum = 0.f;
#pragma unroll
  for (int tt = 0; tt < 4; tt++)
#pragma unroll
    for (int r = 0; r < 16; r++) {
      float e = __expf(sc[tt][r] - mx);
      sc[tt][r] = e;
      lsum += e;
    }
  lsum += __shfl_xor(lsum, 32);
  if (hi == 0) redsum[wave][l31] = lsum;
  __syncthreads();
  float tot = 0.f;
#pragma unroll
  for (int w8 = 0; w8 < 8; w8++) tot += redsum[w8][l31];
  const float inv = 1.f / tot;
#pragma unroll
  for (int tt = 0; tt < 4; tt++)
#pragma unroll
    for (int r = 0; r < 16; r++) sc[tt][r] *= inv;

  // ---- write attn_weights (row q, float4 per reg-group; halves disjoint in k)
  float* wrow = wout_ + ((size_t)bh * Sc + q) * Sc;
#pragma unroll
  for (int tt = 0; tt < 4; tt++) {
#pragma unroll
    for (int g = 0; g < 4; g++) {
      float4 w4;
      w4.x = sc[tt][g * 4 + 0];
      w4.y = sc[tt][g * 4 + 1];
      w4.z = sc[tt][g * 4 + 2];
      w4.w = sc[tt][g * 4 + 3];
      *(float4*)(wrow + kbase + tt * 32 + g * 8 + hi * 4) = w4;
    }
  }

  // ---- PV: O[q][d] partial over this wave's 128 k.
  // A-fragment (P[q][k], 8 consecutive k) assembled in-register via shfl_xor(32).
  const bf16* VTbh = VTb + (size_t)bh * Dc * Sc;
  f32x16 oacc[2];
#pragma unroll
  for (int nj = 0; nj < 2; nj++)
#pragma unroll
    for (int r = 0; r < 16; r++) oacc[nj][r] = 0.f;

#pragma unroll
  for (int tt = 0; tt < 4; tt++) {
    const int k0 = kbase + tt * 32;
#pragma unroll
    for (int st = 0; st < 2; st++) {
      bf16x8 pa;
#pragma unroll
      for (int r = 0; r < 4; r++) {
        const float own = hi ? sc[tt][8 * st + 4 + r] : sc[tt][8 * st + r];
        const float oth = hi ? sc[tt][8 * st + r] : sc[tt][8 * st + 4 + r];
        const float rec = __shfl_xor(oth, 32);
        pa[r] = (bf16)(hi ? rec : own);
        pa[4 + r] = (bf16)(hi ? own : rec);
      }
#pragma unroll
      for (int nj = 0; nj < 2; nj++) {
        const bf16x8 bv = *(const bf16x8*)(VTbh + (size_t)(nj * 32 + l31) * Sc + k0 + st * 16 + hi * 8);
        oacc[nj] = __builtin_amdgcn_mfma_f32_32x32x16_bf16(pa, bv, oacc[nj], 0, 0, 0);
      }
    }
  }

  // ---- two-stage cross-wave O reduction (waves 4-7 add into slots 0-3)
  __syncthreads();  // redsum reads done before Os overwrites nothing, but keep ordering w/ weights phase loads
  if (wave < 4) {
#pragma unroll
    for (int nj = 0; nj < 2; nj++)
#pragma unroll
      for (int rg = 0; rg < 16; rg++) {
        const int qq = (rg & 3) + 8 * (rg >> 2) + 4 * hi;
        Os[wave][qq][nj * 32 + l31] = oacc[nj][rg];
      }
  }
  __syncthreads();
  if (wave >= 4) {
#pragma unroll
    for (int nj = 0; nj < 2; nj++)
#pragma unroll
      for (int rg = 0; rg < 16; rg++) {
        const int qq = (rg & 3) + 8 * (rg >> 2) + 4 * hi;
        Os[wave - 4][qq][nj * 32 + l31] += oacc[nj][rg];
      }
  }
  __syncthreads();
  {
    const int qq = t >> 4, dd = (t & 15) * 4;  // 512 threads: 32 rows x 16 col-groups
    bf16x4 ov;
#pragma unroll
    for (int j = 0; j < 4; j++) {
      float vs = Os[0][qq][dd + j] + Os[1][qq][dd + j] + Os[2][qq][dd + j] + Os[3][qq][dd + j];
      ov[j] = (bf16)vs;
    }
    *(bf16x4*)(ctx + ((size_t)(b * Sc + q0 + qq)) * Ec + h * Dc + dd) = ov;
  }
}

// ---------------------------------------------------------------------------
extern "C" void kernel_launch(void* const* d_in, const int* in_sizes, int n_in,
                              void* d_out, int out_size, void* d_ws, size_t ws_size,
                              hipStream_t stream) {
  const float* q = (const float*)d_in[0];
  const float* k = (const float*)d_in[1];
  const float* v = (const float*)d_in[2];
  const uint8_t* mask = (const uint8_t*)d_in[3];
  const float* Wq = (const float*)d_in[4];
  const float* bq = (const float*)d_in[5];
  const float* Wk = (const float*)d_in[6];
  const float* bk = (const float*)d_in[7];
  const float* Wv = (const float*)d_in[8];
  const float* bv = (const float*)d_in[9];
  const float* Wo = (const float*)d_in[10];
  const float* bo = (const float*)d_in[11];

  // Workspace map (bf16 elements unless noted), ~56MB + 4B:
  //   [0,12M): xb (query,key_,value bf16); [0,4M) reused as ctx after GEMMs,
  //   [4M,8M) reused as VT after projection GEMMs.
  //   [12M,16M): wT (Wq,Wk,Wv,Wo transposed bf16)
  //   [16M,28M): Qb, Kb, Vb head-split bf16 (contiguous -> z-offset in gemm)
  //   byte offset 56MB: mask-stride flag (int)
  bf16* wsb = (bf16*)d_ws;
  bf16* xb = wsb;
  bf16* ctx = wsb;                               // reuse (safe: xb consumed before attn)
  bf16* VTb = wsb + (size_t)4 * 1024 * 1024;     // reuse of xb key region (after gemm_proj)
  bf16* wT = wsb + (size_t)12 * 1024 * 1024;
  bf16* Qb = wsb + (size_t)16 * 1024 * 1024;
  bf16* Kb = wsb + (size_t)20 * 1024 * 1024;
  bf16* Vb = wsb + (size_t)24 * 1024 * 1024;
  int* mflag = (int*)((char*)d_ws + (size_t)56 * 1024 * 1024);

  float* outf = (float*)d_out;                   // attn_output [4,1024,1024]
  float* attnw = outf + (size_t)4 * 1024 * 1024; // attn_weights [4,16,1024,1024]

  detect_mask_kernel<<<1, 64, 0, stream>>>(mask, mflag);
  convert_x_kernel<<<2048, 256, 0, stream>>>(q, k, v, xb);
  convtrans_w_kernel<<<dim3(16, 16, 4), 256, 0, stream>>>(Wq, Wk, Wv, Wo, wT);
  gemm128_kernel<1><<<dim3(8, 32, 3), 256, 0, stream>>>(xb, wT, bq, bk, bv, Qb, nullptr);
  transpose_v_kernel<<<dim3(16, 64), 256, 0, stream>>>(Vb, VTb);
  attn_kernel<<<dim3(32, 16, 4), 512, 0, stream>>>(Qb, Kb, VTb, mask, mflag, attnw, ctx);
  gemm128_kernel<0><<<dim3(8, 32, 1), 256, 0, stream>>>(ctx, wT + (size_t)3 * 1024 * 1024,
                                                        bo, bo, bo, nullptr, outf);
}

// Round 5
// 258.292 us; speedup vs baseline: 1.1097x; 1.0884x over previous
//
#include <hip/hip_runtime.h>
#include <stdint.h>

typedef __bf16 bf16;
typedef bf16 bf16x2 __attribute__((ext_vector_type(2)));
typedef bf16 bf16x4 __attribute__((ext_vector_type(4)));
typedef bf16 bf16x8 __attribute__((ext_vector_type(8)));
typedef float f32x4 __attribute__((ext_vector_type(4)));
typedef float f32x16 __attribute__((ext_vector_type(16)));

static constexpr int Bc = 4, Sc = 1024, Ec = 1024, Hc = 16, Dc = 64, BSc = 4096;

__device__ __forceinline__ void gld_lds16(const void* g, void* s) {
  __builtin_amdgcn_global_load_lds((const __attribute__((address_space(1))) void*)g,
                                   (__attribute__((address_space(3))) void*)s, 16, 0, 0);
}

// ---------------------------------------------------------------------------
// Mask element-stride detection (u8 vs 4-byte encodings) + allTrue init.
__global__ void detect_mask_kernel(const uint8_t* __restrict__ mask, int* flag) {
  if (threadIdx.x == 0 && blockIdx.x == 0) {
    bool everyGroupHasZero = true;
    bool anyNonzero = false;
    for (int j = 0; j < 16; ++j) {
      bool z = false;
      for (int bjj = 0; bjj < 4; ++bjj) {
        uint8_t byte = mask[4 * j + bjj];
        if (byte == 0) z = true;
        if (byte != 0) anyNonzero = true;
      }
      if (!z) everyGroupHasZero = false;
    }
    flag[0] = (everyGroupHasZero && anyNonzero) ? 4 : 1;
    flag[1] = 1;  // allTrue, refined by scan_mask_kernel
  }
}

// Full-mask scan: clears flag[1] if any element is false. Deterministic
// (pure function of the input mask). All-true => zero atomics issued.
__global__ __launch_bounds__(256) void scan_mask_kernel(const uint8_t* __restrict__ mask,
                                                        int* __restrict__ mflag) {
  const int stride = mflag[0];
  bool ok = true;
  const uint4* p = (const uint4*)mask;
  if (stride == 1) {
    const int n = (Bc * Sc * Sc) / 16;  // uint4 count over bytes
    for (int i = blockIdx.x * blockDim.x + threadIdx.x; i < n; i += gridDim.x * blockDim.x) {
      uint4 w = p[i];
      uint32_t z = 0;
      z |= (w.x - 0x01010101u) & ~w.x;
      z |= (w.y - 0x01010101u) & ~w.y;
      z |= (w.z - 0x01010101u) & ~w.z;
      z |= (w.w - 0x01010101u) & ~w.w;
      if (z & 0x80808080u) ok = false;  // some byte == 0
    }
  } else {
    const int n = (Bc * Sc * Sc) / 4;  // uint4 count over words
    for (int i = blockIdx.x * blockDim.x + threadIdx.x; i < n; i += gridDim.x * blockDim.x) {
      uint4 w = p[i];
      if (w.x == 0u || w.y == 0u || w.z == 0u || w.w == 0u) ok = false;
    }
  }
  if (!ok) atomicAnd(&mflag[1], 0);
}

// ---------------------------------------------------------------------------
// fp32 -> bf16 for query/key_/value (3 x 4M elements)
__global__ __launch_bounds__(256) void convert_x_kernel(
    const float* __restrict__ q, const float* __restrict__ k, const float* __restrict__ v,
    bf16* __restrict__ xb) {
  const int n4 = (BSc * Ec) / 4;
  for (int i = blockIdx.x * blockDim.x + threadIdx.x; i < 3 * n4; i += gridDim.x * blockDim.x) {
    int which = i / n4;
    int off = i - which * n4;
    const float4* src = (which == 0) ? (const float4*)q : (which == 1) ? (const float4*)k : (const float4*)v;
    float4 f = src[off];
    bf16x4 o;
    o[0] = (bf16)f.x; o[1] = (bf16)f.y; o[2] = (bf16)f.z; o[3] = (bf16)f.w;
    *(bf16x4*)(xb + (size_t)which * BSc * Ec + (size_t)off * 4) = o;
  }
}

// ---------------------------------------------------------------------------
// W [K][N] fp32 -> WT [N][K] bf16
__global__ __launch_bounds__(256) void convtrans_w_kernel(
    const float* __restrict__ Wq, const float* __restrict__ Wk,
    const float* __restrict__ Wv, const float* __restrict__ Wo,
    bf16* __restrict__ wT) {
  __shared__ float tile[64][65];
  const int k0 = blockIdx.x * 64, n0 = blockIdx.y * 64, z = blockIdx.z;
  const float* W = (z == 0) ? Wq : (z == 1) ? Wk : (z == 2) ? Wv : Wo;
  bf16* out = wT + (size_t)z * Ec * Ec;
  const int t = threadIdx.x;
#pragma unroll
  for (int p = 0; p < 16; p++) {
    int r = p * 4 + (t >> 6), c = t & 63;
    tile[r][c] = W[(size_t)(k0 + r) * Ec + n0 + c];
  }
  __syncthreads();
#pragma unroll
  for (int p = 0; p < 8; p++) {
    int n = p * 8 + (t >> 5), kk = (t & 31) * 2;
    bf16x2 v2;
    v2[0] = (bf16)tile[kk][n];
    v2[1] = (bf16)tile[kk + 1][n];
    *(bf16x2*)(out + (size_t)(n0 + n) * Ec + k0 + kk) = v2;
  }
}

// ---------------------------------------------------------------------------
// 128x128-tile bf16 GEMM. MODE 0: fp32 [M][N] out. MODE 1: bf16 head-split
// [B,H,S,D] out, z-offset per tensor; z==0 (Q) is pre-scaled by 1/sqrt(D)=0.125
// (exact power-of-2: identical bf16 rounding, removes scaling from attn).
template <int MODE>
__global__ __launch_bounds__(256) void gemm128_kernel(
    const bf16* __restrict__ A_, const bf16* __restrict__ W_,
    const float* __restrict__ bias0, const float* __restrict__ bias1, const float* __restrict__ bias2,
    bf16* __restrict__ outb_, float* __restrict__ outf) {
  constexpr int K = 1024, N = 1024;
  const int z = blockIdx.z;
  const bf16* A = A_ + (size_t)z * BSc * K;
  const bf16* Wt = W_ + (size_t)z * N * K;
  const float* bias = (z == 0) ? bias0 : (z == 1) ? bias1 : bias2;
  bf16* outb = outb_ + (size_t)z * Bc * Hc * Sc * Dc;
  const float oscale = (MODE == 1 && z == 0) ? 0.125f : 1.0f;
  const int n0 = blockIdx.x * 128, m0 = blockIdx.y * 128;

  __shared__ bf16 As[128 * 64];
  __shared__ bf16 Bs[128 * 64];
  const int t = threadIdx.x, wave = t >> 6, lane = t & 63;
  const int wr = wave >> 1, wc = wave & 1;

  f32x4 acc[4][4];
#pragma unroll
  for (int i = 0; i < 4; i++)
#pragma unroll
    for (int j = 0; j < 4; j++)
#pragma unroll
      for (int r = 0; r < 4; r++) acc[i][j][r] = 0.f;

  const int srow = (lane >> 3);
  const int scol = (lane & 7) * 8;

  for (int kt = 0; kt < K; kt += 64) {
#pragma unroll
    for (int i = 0; i < 4; i++) {
      const int chunk = i * 4 + wave;
      const int row = chunk * 8 + srow;
      gld_lds16(A + (size_t)(m0 + row) * K + kt + scol, &As[chunk * 512]);
      gld_lds16(Wt + (size_t)(n0 + row) * K + kt + scol, &Bs[chunk * 512]);
    }
    __syncthreads();
#pragma unroll
    for (int kk = 0; kk < 2; kk++) {
      bf16x8 af[4], bg[4];
#pragma unroll
      for (int i = 0; i < 4; i++) {
        af[i] = *(const bf16x8*)&As[(64 * wr + i * 16 + (lane & 15)) * 64 + kk * 32 + (lane >> 4) * 8];
        bg[i] = *(const bf16x8*)&Bs[(64 * wc + i * 16 + (lane & 15)) * 64 + kk * 32 + (lane >> 4) * 8];
      }
#pragma unroll
      for (int mi = 0; mi < 4; mi++)
#pragma unroll
        for (int ni = 0; ni < 4; ni++)
          acc[mi][ni] = __builtin_amdgcn_mfma_f32_16x16x32_bf16(af[mi], bg[ni], acc[mi][ni], 0, 0, 0);
    }
    __syncthreads();
  }

#pragma unroll
  for (int mi = 0; mi < 4; mi++) {
#pragma unroll
    for (int ni = 0; ni < 4; ni++) {
      const int col = n0 + 64 * wc + ni * 16 + (lane & 15);
      const float bvl = bias[col];
#pragma unroll
      for (int r = 0; r < 4; r++) {
        const int row = m0 + 64 * wr + mi * 16 + (lane >> 4) * 4 + r;
        const float v = (acc[mi][ni][r] + bvl) * oscale;
        if (MODE == 0) {
          outf[(size_t)row * N + col] = v;
        } else {
          const int bidx = row >> 10, s = row & 1023, hh = col >> 6, d = col & 63;
          outb[(((size_t)bidx * Hc + hh) * Sc + s) * Dc + d] = (bf16)v;
        }
      }
    }
  }
}

// ---------------------------------------------------------------------------
// V [bh][S][D] -> VT [bh][D][S] (bf16)
__global__ __launch_bounds__(256) void transpose_v_kernel(const bf16* __restrict__ Vb,
                                                          bf16* __restrict__ VTb) {
  __shared__ bf16 tile[64][66];
  const int s0 = blockIdx.x * 64, bh = blockIdx.y;
  const bf16* src = Vb + (size_t)bh * Sc * Dc;
  bf16* dst = VTb + (size_t)bh * Dc * Sc;
  const int t = threadIdx.x;
#pragma unroll
  for (int p = 0; p < 8; p++) {
    int s = p * 8 + (t >> 5), d = (t & 31) * 2;
    *(bf16x2*)&tile[s][d] = *(const bf16x2*)(src + (size_t)(s0 + s) * Dc + d);
  }
  __syncthreads();
#pragma unroll
  for (int p = 0; p < 8; p++) {
    int d = p * 8 + (t >> 5), s = (t & 31) * 2;
    bf16x2 v2;
    v2[0] = tile[s][d];
    v2[1] = tile[s + 1][d];
    *(bf16x2*)(dst + (size_t)d * Sc + s0 + s) = v2;
  }
}

// ---------------------------------------------------------------------------
// Fused attention v3. Per WG (b,h,32 q-rows), 8 waves, wave w owns k-range
// [w*128,(w+1)*128). Round-5 changes (anti-divergence):
//  - mask loads skipped when mflag[1] (all-true); Q pre-scaled in projection
//  - weights stored via per-wave LDS tile: 8-row x 128B dense nontemporal stores
//  - PV A-fragments read back from the same LDS tile (no shfl_xor chain)
__global__ __launch_bounds__(512, 3) void attn_kernel(
    const bf16* __restrict__ Qb, const bf16* __restrict__ Kb, const bf16* __restrict__ VTb,
    const uint8_t* __restrict__ mask, const int* __restrict__ mflag,
    float* __restrict__ wout_, bf16* __restrict__ ctx) {
  const int q0 = blockIdx.x * 32, h = blockIdx.y, b = blockIdx.z;
  const int bh = b * Hc + h;
  const int t = threadIdx.x, wave = t >> 6, lane = t & 63;
  const int l31 = lane & 31, hi = lane >> 5;
  const int q = q0 + l31;

  // pool: per-wave P tiles [8][32][33] f32 during softmax/PV phase,
  //       aliased as Os [4][32][65] f32 after the post-PV barrier.
  __shared__ float pool[8 * 32 * 33];
  __shared__ float redmax[8][32];
  __shared__ float redsum[8][32];

  const bf16* Qp = Qb + ((size_t)bh * Sc + q) * Dc;
  bf16x8 qf[4];
#pragma unroll
  for (int ks = 0; ks < 4; ks++) qf[ks] = *(const bf16x8*)(Qp + ks * 16 + hi * 8);

  const int kbase = wave * 128;
  const bf16* Kbh = Kb + (size_t)bh * Sc * Dc;

  // ---- scores: 4 tiles of 32k x 32q, D[k][q] (Q pre-scaled by 0.125)
  f32x16 sc[4];
#pragma unroll
  for (int tt = 0; tt < 4; tt++) {
    const bf16* Kp = Kbh + (size_t)(kbase + tt * 32 + l31) * Dc;
    f32x16 a;
#pragma unroll
    for (int r = 0; r < 16; r++) a[r] = 0.f;
#pragma unroll
    for (int ks = 0; ks < 4; ks++) {
      bf16x8 kf = *(const bf16x8*)(Kp + ks * 16 + hi * 8);
      a = __builtin_amdgcn_mfma_f32_32x32x16_bf16(kf, qf[ks], a, 0, 0, 0);
    }
    sc[tt] = a;
  }

  // ---- mask (only when not all-true); klocal(reg) = (reg&3)+8*(reg>>2)+4*hi
  const int allTrue = mflag[1];
  if (!allTrue) {
    const int mstride = mflag[0];
    if (mstride == 1) {
      const uint8_t* mrow = mask + (size_t)(b * Sc + q) * Sc;
#pragma unroll
      for (int tt = 0; tt < 4; tt++) {
#pragma unroll
        for (int g = 0; g < 4; g++) {
          const int kg = kbase + tt * 32 + g * 8 + hi * 4;
          const uint32_t mw = *(const uint32_t*)(mrow + kg);
#pragma unroll
          for (int r = 0; r < 4; r++) {
            if (((mw >> (8 * r)) & 0xffu) == 0u) sc[tt][g * 4 + r] = -1e9f;
          }
        }
      }
    } else {
      const uint8_t* mrow = mask + (size_t)(b * Sc + q) * Sc * 4;
#pragma unroll
      for (int tt = 0; tt < 4; tt++) {
#pragma unroll
        for (int g = 0; g < 4; g++) {
          const int kg = kbase + tt * 32 + g * 8 + hi * 4;
          const uint4 m4 = *(const uint4*)(mrow + (size_t)4 * kg);
          const uint32_t w[4] = {m4.x, m4.y, m4.z, m4.w};
#pragma unroll
          for (int r = 0; r < 4; r++) {
            if (w[r] == 0u) sc[tt][g * 4 + r] = -1e9f;
          }
        }
      }
    }
  }

  // ---- softmax reductions: lane-local -> xor32 -> 8-wave LDS
  float mx = -3.0e38f;
#pragma unroll
  for (int tt = 0; tt < 4; tt++)
#pragma unroll
    for (int r = 0; r < 16; r++) mx = fmaxf(mx, sc[tt][r]);
  mx = fmaxf(mx, __shfl_xor(mx, 32));
  if (hi == 0) redmax[wave][l31] = mx;
  __syncthreads();
#pragma unroll
  for (int w8 = 0; w8 < 8; w8++) mx = fmaxf(mx, redmax[w8][l31]);

  float lsum = 0.f;
#pragma unroll
  for (int tt = 0; tt < 4; tt++)
#pragma unroll
    for (int r = 0; r < 16; r++) {
      float e = __expf(sc[tt][r] - mx);
      sc[tt][r] = e;
      lsum += e;
    }
  lsum += __shfl_xor(lsum, 32);
  if (hi == 0) redsum[wave][l31] = lsum;
  __syncthreads();
  float tot = 0.f;
#pragma unroll
  for (int w8 = 0; w8 < 8; w8++) tot += redsum[w8][l31];
  const float inv = 1.f / tot;

  // ---- per-tile: normalize into LDS P tile, dense weights stores, PV
  float* Pt = pool + wave * (32 * 33);
  const bf16* VTbh = VTb + (size_t)bh * Dc * Sc;
  float* wbase = wout_ + ((size_t)bh * Sc + q0) * Sc + kbase;
  f32x16 oacc[2];
#pragma unroll
  for (int nj = 0; nj < 2; nj++)
#pragma unroll
    for (int r = 0; r < 16; r++) oacc[nj][r] = 0.f;

#pragma unroll
  for (int tt = 0; tt < 4; tt++) {
    // P[q=l31][k = 8g+4hi .. +3] = sc*inv  (f32x4 per group)
#pragma unroll
    for (int g = 0; g < 4; g++) {
      f32x4 w4;
#pragma unroll
      for (int r = 0; r < 4; r++) w4[r] = sc[tt][g * 4 + r] * inv;
      *(f32x4*)&Pt[l31 * 33 + g * 8 + hi * 4] = w4;
    }
    // dense weights stores: 4 instrs x (8 rows x 128B)
#pragma unroll
    for (int i = 0; i < 4; i++) {
      const int q2 = 8 * i + (lane >> 3), kk = (lane & 7) * 4;
      const f32x4 v4 = *(const f32x4*)&Pt[q2 * 33 + kk];
      __builtin_nontemporal_store(v4, (f32x4*)(wbase + (size_t)q2 * Sc + tt * 32 + kk));
    }
    // PV: A-frag pa[j] = P[q=l31][st*16 + hi*8 + j] straight from LDS
#pragma unroll
    for (int st = 0; st < 2; st++) {
      const f32x4 a0 = *(const f32x4*)&Pt[l31 * 33 + st * 16 + hi * 8];
      const f32x4 a1 = *(const f32x4*)&Pt[l31 * 33 + st * 16 + hi * 8 + 4];
      bf16x8 pa;
#pragma unroll
      for (int j = 0; j < 4; j++) {
        pa[j] = (bf16)a0[j];
        pa[4 + j] = (bf16)a1[j];
      }
#pragma unroll
      for (int nj = 0; nj < 2; nj++) {
        const bf16x8 bv = *(const bf16x8*)(VTbh + (size_t)(nj * 32 + l31) * Sc + kbase + tt * 32 + st * 16 + hi * 8);
        oacc[nj] = __builtin_amdgcn_mfma_f32_32x32x16_bf16(pa, bv, oacc[nj], 0, 0, 0);
      }
    }
  }

  // ---- two-stage cross-wave O reduction in pool (aliases Pt; barrier-safe)
  __syncthreads();
  float* Os = pool;  // [4][32][65]
  if (wave < 4) {
#pragma unroll
    for (int nj = 0; nj < 2; nj++)
#pragma unroll
      for (int rg = 0; rg < 16; rg++) {
        const int qq = (rg & 3) + 8 * (rg >> 2) + 4 * hi;
        Os[wave * 2080 + qq * 65 + nj * 32 + l31] = oacc[nj][rg];
      }
  }
  __syncthreads();
  if (wave >= 4) {
#pragma unroll
    for (int nj = 0; nj < 2; nj++)
#pragma unroll
      for (int rg = 0; rg < 16; rg++) {
        const int qq = (rg & 3) + 8 * (rg >> 2) + 4 * hi;
        Os[(wave - 4) * 2080 + qq * 65 + nj * 32 + l31] += oacc[nj][rg];
      }
  }
  __syncthreads();
  {
    const int qq = t >> 4, dd = (t & 15) * 4;
    bf16x4 ov;
#pragma unroll
    for (int j = 0; j < 4; j++) {
      float vs = Os[0 * 2080 + qq * 65 + dd + j] + Os[1 * 2080 + qq * 65 + dd + j] +
                 Os[2 * 2080 + qq * 65 + dd + j] + Os[3 * 2080 + qq * 65 + dd + j];
      ov[j] = (bf16)vs;
    }
    *(bf16x4*)(ctx + ((size_t)(b * Sc + q0 + qq)) * Ec + h * Dc + dd) = ov;
  }
}

// ---------------------------------------------------------------------------
extern "C" void kernel_launch(void* const* d_in, const int* in_sizes, int n_in,
                              void* d_out, int out_size, void* d_ws, size_t ws_size,
                              hipStream_t stream) {
  const float* q = (const float*)d_in[0];
  const float* k = (const float*)d_in[1];
  const float* v = (const float*)d_in[2];
  const uint8_t* mask = (const uint8_t*)d_in[3];
  const float* Wq = (const float*)d_in[4];
  const float* bq = (const float*)d_in[5];
  const float* Wk = (const float*)d_in[6];
  const float* bk = (const float*)d_in[7];
  const float* Wv = (const float*)d_in[8];
  const float* bv = (const float*)d_in[9];
  const float* Wo = (const float*)d_in[10];
  const float* bo = (const float*)d_in[11];

  bf16* wsb = (bf16*)d_ws;
  bf16* xb = wsb;
  bf16* ctx = wsb;
  bf16* VTb = wsb + (size_t)4 * 1024 * 1024;
  bf16* wT = wsb + (size_t)12 * 1024 * 1024;
  bf16* Qb = wsb + (size_t)16 * 1024 * 1024;
  bf16* Kb = wsb + (size_t)20 * 1024 * 1024;
  bf16* Vb = wsb + (size_t)24 * 1024 * 1024;
  int* mflag = (int*)((char*)d_ws + (size_t)56 * 1024 * 1024);

  float* outf = (float*)d_out;
  float* attnw = outf + (size_t)4 * 1024 * 1024;

  detect_mask_kernel<<<1, 64, 0, stream>>>(mask, mflag);
  scan_mask_kernel<<<1024, 256, 0, stream>>>(mask, mflag);
  convert_x_kernel<<<2048, 256, 0, stream>>>(q, k, v, xb);
  convtrans_w_kernel<<<dim3(16, 16, 4), 256, 0, stream>>>(Wq, Wk, Wv, Wo, wT);
  gemm128_kernel<1><<<dim3(8, 32, 3), 256, 0, stream>>>(xb, wT, bq, bk, bv, Qb, nullptr);
  transpose_v_kernel<<<dim3(16, 64), 256, 0, stream>>>(Vb, VTb);
  attn_kernel<<<dim3(32, 16, 4), 512, 0, stream>>>(Qb, Kb, VTb, mask, mflag, attnw, ctx);
  gemm128_kernel<0><<<dim3(8, 32, 1), 256, 0, stream>>>(ctx, wT + (size_t)3 * 1024 * 1024,
                                                        bo, bo, bo, nullptr, outf);
}